// Round 12
// baseline (271.208 us; speedup 1.0000x reference)
//
#include <hip/hip_runtime.h>
#include <float.h>

#define N_PART 262144
#define GRID_DIM 256
#define NUM_CELLS (GRID_DIM * GRID_DIM)
#define KP 32                          // padded slots per cell (= reference K)
#define MAXNB 64

// ---------------- ws layout (all 256B-aligned) ----------------
// params : 3 uints (combined minx/miny/maxh bits; written by bin block 0)
// counts : NUM_CELLS+1 ints   (zeroed in D1; [NUM_CELLS] stays 0 = clip row)
// bMinX/Y/H : 1024 floats each (per-block reduce partials)
// tableA : (NUM_CELLS+1)*KP ints   (raw ids, arrival order)
// Qpad   : (NUM_CELLS+1)*KP + 64 float4  ({x, y, id-bits, 0}, id-sorted)
// cinfo  : NUM_CELLS * 4 int4  (9-cell prefix sums, 64B/cell = 1 line/wave)
//
// RESUBMISSION of r11: container failed twice, but audit found no failure
// mechanism (no coop launch, bounded loops, all indices in-bounds, ws
// smaller than r10's passing 50MB, re-poison safe). Harness flakiness has
// precedent (r8's 780s pushes). Re-running the experiment unchanged.
//
// Dispatch economics (r3/r5): grid.sync costs ~ a dispatch boundary, so no
// cooperative fusion. FOUR ordinary full-occupancy dispatches.
// Query economics (r2..r10): cell-order = cheap gathers + random 256B
// writes (~1.4TB/s); id-order = sequential writes + private gathers
// (~240MB fetch). This round keeps id-order and removes every non-window
// gather from the query head (pos2/sup are SEQUENTIAL in id order; cell +
// S recomputed from them) and the linR scatter + sup gather from rank.

__global__ __launch_bounds__(256) void prep_kernel(
        const float2* __restrict__ pos2, const float* __restrict__ sup,
        int* __restrict__ counts,
        float* __restrict__ bMinX, float* __restrict__ bMinY,
        float* __restrict__ bMaxH) {
    __shared__ unsigned s_minx, s_miny, s_maxh;
    int t = threadIdx.x, b = blockIdx.x;
    int tid = b * 256 + t;
    if (tid <= NUM_CELLS) counts[tid] = 0;
    if (t == 0) { s_minx = 0x7f7fffffu; s_miny = 0x7f7fffffu; s_maxh = 0u; }
    __syncthreads();
    float2 p = pos2[tid];
    float  h = sup[tid];
    // non-negative floats: uint compare == float compare
    atomicMin(&s_minx, __float_as_uint(p.x));
    atomicMin(&s_miny, __float_as_uint(p.y));
    atomicMax(&s_maxh, __float_as_uint(h));
    __syncthreads();
    if (t == 0) {
        bMinX[b] = __uint_as_float(s_minx);
        bMinY[b] = __uint_as_float(s_miny);
        bMaxH[b] = __uint_as_float(s_maxh);
    }
}

__global__ __launch_bounds__(256) void bin_kernel(
        const float2* __restrict__ pos2,
        const float* __restrict__ bMinX, const float* __restrict__ bMinY,
        const float* __restrict__ bMaxH,
        unsigned* __restrict__ params,
        int* __restrict__ counts, int* __restrict__ tableA) {
    __shared__ unsigned s_minx, s_miny, s_maxh;
    int t = threadIdx.x;
    int tid = blockIdx.x * 256 + t;
    // redundant per-block combine of 1024 partials: min/max exact and
    // order-independent -> identical result in every block
    if (t == 0) { s_minx = 0x7f7fffffu; s_miny = 0x7f7fffffu; s_maxh = 0u; }
    __syncthreads();
    {
        float mx = FLT_MAX, my = FLT_MAX, mh = 0.0f;
        for (int k = t; k < 1024; k += 256) {
            mx = fminf(mx, bMinX[k]);
            my = fminf(my, bMinY[k]);
            mh = fmaxf(mh, bMaxH[k]);
        }
        atomicMin(&s_minx, __float_as_uint(mx));
        atomicMin(&s_miny, __float_as_uint(my));
        atomicMax(&s_maxh, __float_as_uint(mh));
    }
    __syncthreads();
    if (blockIdx.x == 0 && t == 0) {    // publish combined params for query
        params[0] = s_minx; params[1] = s_miny; params[2] = s_maxh;
    }
    float hmax  = __uint_as_float(s_maxh);
    float qminx = __uint_as_float(s_minx) - hmax;
    float qminy = __uint_as_float(s_miny) - hmax;
    float2 p = pos2[tid];
    int cx = (int)ceilf((p.x - qminx) / hmax);
    int cy = (int)ceilf((p.y - qminy) / hmax);
    cx = min(max(cx, 0), GRID_DIM - 1);
    cy = min(max(cy, 0), GRID_DIM - 1);
    int c = cx + GRID_DIM * cy;
    int slot = atomicAdd(&counts[c], 1);
    if (slot < KP) tableA[(c << 5) + slot] = tid;   // Poisson(4): never >32
}

// (cell,slot)-parallel ordered emit (r9/r10-verified core): thread (c,s)
// handles arrival slots s, s+8, ... rank = #(smaller ids in row) puts each
// record at its id-sorted position (stable argsort semantics). No sup
// gather (S moved to query), no linR scatter (query reconstructs from
// sequential pos2/sup). cinfo = 9-cell prefix sums at 64B stride -> the
// query's setup costs exactly one cache line.
__global__ __launch_bounds__(256) void rank_kernel(
        const float2* __restrict__ pos2,
        const int* __restrict__ counts, const int* __restrict__ tableA,
        float4* __restrict__ Qpad, int4* __restrict__ cinfo) {
    int tid = blockIdx.x * 256 + threadIdx.x;   // NUM_CELLS*8 threads
    int c   = tid >> 3;
    int s0  = tid & 7;
    int cnt = min(counts[c], KP);
    const int* row = tableA + (c << 5);
    for (int sl = s0; sl < cnt; sl += 8) {
        int id = row[sl];
        int rank = 0;
        for (int k = 0; k < cnt; k++) rank += (row[k] < id);
        float2 p = pos2[id];            // bitwise copy: query numerics identical
        Qpad[(c << 5) + rank] = make_float4(p.x, p.y, __int_as_float(id), 0.0f);
    }
    if (s0 == 0) {                      // one thread per cell: prefix sums
        const int offs[9] = {-257, -1, 255, -256, 0, 256, -255, 1, 257};
        int cum = 0;
        int v[9];
#pragma unroll
        for (int o = 0; o < 9; o++) {
            int cl = min(max(c + offs[o], 0), NUM_CELLS);   // clip, dups incl.
            cum += min(counts[cl], KP);
            v[o] = cum;
        }
        cinfo[(c << 2) + 0] = make_int4(v[0], v[1], v[2], v[3]);
        cinfo[(c << 2) + 1] = make_int4(v[4], v[5], v[6], v[7]);
        cinfo[(c << 2) + 2] = make_int4(v[8], 0, 0, 0);
    }
}

// One wave per PARTICLE in ID ORDER (sequential 256B output rows). Head:
// pos2[w]/sup[w] are SEQUENTIAL loads; cell c recomputed with ops identical
// to bin (same params -> same result); S = exact f32 threshold with
//   s2 <= S  <=>  RN(sqrt(s2)) <= h
// (mid = (h+nextafterf(h))/2; mid^2 exact in double, never a 24-bit f32 ->
// no ties; S = largest f32 <= mid^2) -- same verified code since r2, now
// once per wave. cinfo = 1 line. Window gather, masked-ballot stable
// compaction, LDS bounce, epilogue: byte-identical to the r10-passed path.
// Junk lanes clamp to (c<<5): own cell has cnt>=1 so slot 0 is written.
__global__ __launch_bounds__(256) void query_kernel(
        const float2* __restrict__ pos2, const float* __restrict__ sup,
        const unsigned* __restrict__ params,
        const int4* __restrict__ cinfo, const float4* __restrict__ Qpad,
        float* __restrict__ outN, float* __restrict__ outC,
        float* __restrict__ outR) {
#pragma clang fp contract(off)
    __shared__ int   s_id[4][MAXNB];
    __shared__ float s_s2[4][MAXNB];

    int t    = threadIdx.x;
    int lane = t & 63;
    int wsl  = t >> 6;
    int bid  = blockIdx.x;
    int swz  = (bid & 7) * (int)(gridDim.x >> 3) + (bid >> 3);  // bijective XCD
    int w    = __builtin_amdgcn_readfirstlane(swz * 4 + wsl);   // particle id

    float2 pw = pos2[w];                 // sequential across waves
    float  h  = sup[w];
    float px = __int_as_float(__builtin_amdgcn_readfirstlane(__float_as_int(pw.x)));
    float py = __int_as_float(__builtin_amdgcn_readfirstlane(__float_as_int(pw.y)));
    h = __int_as_float(__builtin_amdgcn_readfirstlane(__float_as_int(h)));

    // cell: identical ops to bin_kernel (same params -> identical result)
    float hmax  = __uint_as_float(params[2]);
    float qminx = __uint_as_float(params[0]) - hmax;
    float qminy = __uint_as_float(params[1]) - hmax;
    int cx = (int)ceilf((px - qminx) / hmax);
    int cy = (int)ceilf((py - qminy) / hmax);
    cx = min(max(cx, 0), GRID_DIM - 1);
    cy = min(max(cy, 0), GRID_DIM - 1);
    int c = __builtin_amdgcn_readfirstlane(cx + GRID_DIM * cy);

    // exact f32 threshold for RN(sqrt(s2)) <= h   (h > 0, normal)
    float  hn  = __int_as_float(__float_as_int(h) + 1);     // nextafter(h,inf)
    double mid = 0.5 * ((double)h + (double)hn);
    double t2  = mid * mid;                                  // exact (50 bits)
    float  S   = (float)t2;                                  // RN
    S = ((double)S > t2) ? __int_as_float(__float_as_int(S) - 1) : S;  // RD

    int4 ca = cinfo[(c << 2) + 0];      // one 64B line, uniform
    int4 cb = cinfo[(c << 2) + 1];
    int4 cz = cinfo[(c << 2) + 2];

    const int offs[9] = {-257, -1, 255, -256, 0, 256, -255, 1, 257};
    int cum[10] = {0, ca.x, ca.y, ca.z, ca.w, cb.x, cb.y, cb.z, cb.w, };
    cum[9] = cz.x;
    int T = cum[9];
    int delta[9];
#pragma unroll
    for (int o = 0; o < 9; o++) {
        int cl = min(max(c + offs[o], 0), NUM_CELLS);   // clip, dups at edges
        delta[o] = (cl << 5) - cum[o];                  // idx = ll + delta[o]
    }

    if (T <= 64) {
        // ---- fast path: one candidate per lane ----
        int dsel = delta[0];
#pragma unroll
        for (int m = 1; m < 9; m++)
            dsel = (lane >= cum[m]) ? delta[m] : dsel;
        int idx = (lane < T) ? (lane + dsel) : (c << 5);   // clamp junk lanes
        float4 q = Qpad[idx];                              //  to a hot line
        unsigned long long maskT = (T >= 64) ? ~0ull : ((1ull << T) - 1ull);
        float dx = q.x - px;
        float dy = q.y - py;
        float s2 = dx * dx + dy * dy;          // contract(off): match XLA
        bool keep = (s2 <= S) && (lane < T);   // junk/clamp lanes masked
        unsigned long long bal = __ballot(s2 <= S) & maskT;
        int rank = __builtin_amdgcn_mbcnt_hi(
            (unsigned)(bal >> 32),
            __builtin_amdgcn_mbcnt_lo((unsigned)bal, 0));
        if (keep) {                            // T<=64 -> rank < 64 always
            s_id[wsl][rank] = __float_as_int(q.z);
            s_s2[wsl][rank] = s2;
        }
        int total = (int)__popcll(bal);
        // wave-private LDS, same-wave DS ops ordered: no barrier. Stale
        // entries beyond 'total' discarded by the inb select.
        int   jj = s_id[wsl][lane];
        float ss = s_s2[wsl][lane];
        bool inb = lane < total;
        float rh = __builtin_amdgcn_rsqf(S);   // ~1/h, 1ulp; tol-covered
        float vN = inb ? (float)jj : -1.0f;
        float vR = inb ? __builtin_amdgcn_sqrtf(ss) * rh : 0.0f;
        size_t base = (size_t)w * MAXNB;       // SEQUENTIAL across waves
        outN[base + lane] = vN;
        outR[base + lane] = vR;
        if (lane == 0) outC[w] = (float)total;
    } else {
        // ---- rare path (P(T>64) ~ 1e-5 per cell): batched, re-loads ----
        int total = 0;
        for (int b0 = 0; b0 < T; b0 += 64) {
            int ll = b0 + lane;
            int dsel = delta[0];
#pragma unroll
            for (int m = 1; m < 9; m++)
                dsel = (ll >= cum[m]) ? delta[m] : dsel;
            float4 q = Qpad[ll + dsel];        // <= pad: Qpad padded by 64
            float dx = q.x - px;
            float dy = q.y - py;
            float s2 = dx * dx + dy * dy;
            int rem = T - b0;
            unsigned long long maskT =
                (rem >= 64) ? ~0ull : ((1ull << rem) - 1ull);
            unsigned long long bal = __ballot(s2 <= S) & maskT;
            int rank = __builtin_amdgcn_mbcnt_hi(
                (unsigned)(bal >> 32),
                __builtin_amdgcn_mbcnt_lo((unsigned)bal, 0));
            int ww = total + rank;
            if ((s2 <= S) && (ll < T) && (ww < MAXNB)) {
                s_id[wsl][ww] = __float_as_int(q.z);
                s_s2[wsl][ww] = s2;
            }
            total += (int)__popcll(bal);
        }
        int stored = min(total, MAXNB);
        int   jj = s_id[wsl][lane];
        float ss = s_s2[wsl][lane];
        bool inb = lane < stored;
        float rh = __builtin_amdgcn_rsqf(S);
        float vN = inb ? (float)jj : -1.0f;
        float vR = inb ? __builtin_amdgcn_sqrtf(ss) * rh : 0.0f;
        size_t base = (size_t)w * MAXNB;
        outN[base + lane] = vN;
        outR[base + lane] = vR;
        if (lane == 0) outC[w] = (float)total;
    }
}

extern "C" void kernel_launch(void* const* d_in, const int* in_sizes, int n_in,
                              void* d_out, int out_size, void* d_ws, size_t ws_size,
                              hipStream_t stream) {
    const float2* pos2 = (const float2*)d_in[0];
    const float*  sup  = (const float*)d_in[1];

    char* p = (char*)d_ws;
    auto alloc = [&](size_t bytes) {
        char* q = p;
        p += (bytes + 255) & ~(size_t)255;
        return q;
    };
    unsigned* params = (unsigned*)alloc(256);
    int*    counts = (int*)alloc((size_t)(NUM_CELLS + 1) * 4);
    float*  bMinX  = (float*)alloc(1024 * 4);
    float*  bMinY  = (float*)alloc(1024 * 4);
    float*  bMaxH  = (float*)alloc(1024 * 4);
    int*    tableA = (int*)alloc((size_t)(NUM_CELLS + 1) * KP * 4);
    float4* Qpad   = (float4*)alloc(((size_t)(NUM_CELLS + 1) * KP + 64) * 16);
    int4*   cinfo  = (int4*)alloc((size_t)NUM_CELLS * 4 * 16);

    float* out  = (float*)d_out;
    float* outN = out;                              // N*64 neighbor ids (as f32)
    float* outC = out + (size_t)N_PART * MAXNB;     // N counts
    float* outR = outC + N_PART;                    // N*64 radial

    prep_kernel<<<N_PART / 256, 256, 0, stream>>>(pos2, sup, counts,
                                                  bMinX, bMinY, bMaxH);
    bin_kernel<<<N_PART / 256, 256, 0, stream>>>(pos2, bMinX, bMinY, bMaxH,
                                                 params, counts, tableA);
    // thread per (cell, slot-class): NUM_CELLS*8 threads
    rank_kernel<<<NUM_CELLS * 8 / 256, 256, 0, stream>>>(pos2, counts,
                                                         tableA, Qpad, cinfo);
    // one wave per particle, ID ORDER: N_PART waves = N_PART/4 blocks
    query_kernel<<<N_PART / 4, 256, 0, stream>>>(pos2, sup, params, cinfo,
                                                 Qpad, outN, outC, outR);
}

// Round 13
// 264.423 us; speedup vs baseline: 1.0257x; 1.0257x over previous
//
#include <hip/hip_runtime.h>
#include <float.h>

#define N_PART 262144
#define GRID_DIM 256
#define NUM_CELLS (GRID_DIM * GRID_DIM)
#define KP 32                          // padded slots per cell (= reference K)
#define MAXNB 64

// ---------------- ws layout (all 256B-aligned) ----------------
// params : 3 uints (combined minx/miny/maxh bits; written by bin block 0)
// counts : NUM_CELLS+1 ints   (zeroed in D1; [NUM_CELLS] stays 0 = clip row)
// bMinX/Y/H : 1024 floats each (per-block reduce partials)
// Qraw   : (NUM_CELLS+1)*KP float4  ({x, y, id-bits, h}, arrival order)
// Qpad   : (NUM_CELLS+1)*KP + 64 float4  ({x, y, id-bits, S}, id-sorted)
// linR   : N ints              ((cell<<5)|rank per particle id)
// cinfo  : NUM_CELLS * 4 int4  (9-cell prefix sums, 64B/cell = 1 line/wave)
//
// Dispatch economics (r3/r5): grid.sync costs ~ a dispatch boundary, so no
// cooperative fusion. FOUR ordinary full-occupancy dispatches.
// Query economics (r10 vs r12 A/B): uniform-load head (linR + S-in-record,
// 102.7us) beats per-wave cell/S recompute (112us) -> r10 body restored.
// Build economics (this round): bin holds {x,y,id,h} in registers at slot-
// claim time, so it writes the FULL record; rank becomes row-local with
// ZERO random gathers (was: 262144 x 8B pos2 gather + sup gather).

__global__ __launch_bounds__(256) void prep_kernel(
        const float2* __restrict__ pos2, const float* __restrict__ sup,
        int* __restrict__ counts,
        float* __restrict__ bMinX, float* __restrict__ bMinY,
        float* __restrict__ bMaxH) {
    __shared__ unsigned s_minx, s_miny, s_maxh;
    int t = threadIdx.x, b = blockIdx.x;
    int tid = b * 256 + t;
    if (tid <= NUM_CELLS) counts[tid] = 0;
    if (t == 0) { s_minx = 0x7f7fffffu; s_miny = 0x7f7fffffu; s_maxh = 0u; }
    __syncthreads();
    float2 p = pos2[tid];
    float  h = sup[tid];
    // non-negative floats: uint compare == float compare
    atomicMin(&s_minx, __float_as_uint(p.x));
    atomicMin(&s_miny, __float_as_uint(p.y));
    atomicMax(&s_maxh, __float_as_uint(h));
    __syncthreads();
    if (t == 0) {
        bMinX[b] = __uint_as_float(s_minx);
        bMinY[b] = __uint_as_float(s_miny);
        bMaxH[b] = __uint_as_float(s_maxh);
    }
}

__global__ __launch_bounds__(256) void bin_kernel(
        const float2* __restrict__ pos2, const float* __restrict__ sup,
        const float* __restrict__ bMinX, const float* __restrict__ bMinY,
        const float* __restrict__ bMaxH,
        unsigned* __restrict__ params,
        int* __restrict__ counts, float4* __restrict__ Qraw) {
    __shared__ unsigned s_minx, s_miny, s_maxh;
    int t = threadIdx.x;
    int tid = blockIdx.x * 256 + t;
    // redundant per-block combine of 1024 partials: min/max exact and
    // order-independent -> identical result in every block
    if (t == 0) { s_minx = 0x7f7fffffu; s_miny = 0x7f7fffffu; s_maxh = 0u; }
    __syncthreads();
    {
        float mx = FLT_MAX, my = FLT_MAX, mh = 0.0f;
        for (int k = t; k < 1024; k += 256) {
            mx = fminf(mx, bMinX[k]);
            my = fminf(my, bMinY[k]);
            mh = fmaxf(mh, bMaxH[k]);
        }
        atomicMin(&s_minx, __float_as_uint(mx));
        atomicMin(&s_miny, __float_as_uint(my));
        atomicMax(&s_maxh, __float_as_uint(mh));
    }
    __syncthreads();
    if (blockIdx.x == 0 && t == 0) {    // publish combined params (query
        params[0] = s_minx; params[1] = s_miny; params[2] = s_maxh;  // unused
    }                                   //  now, kept for debug)
    float hmax  = __uint_as_float(s_maxh);
    float qminx = __uint_as_float(s_minx) - hmax;
    float qminy = __uint_as_float(s_miny) - hmax;
    float2 p = pos2[tid];
    float  h = sup[tid];                // sequential load
    int cx = (int)ceilf((p.x - qminx) / hmax);
    int cy = (int)ceilf((p.y - qminy) / hmax);
    cx = min(max(cx, 0), GRID_DIM - 1);
    cy = min(max(cy, 0), GRID_DIM - 1);
    int c = cx + GRID_DIM * cy;
    int slot = atomicAdd(&counts[c], 1);
    if (slot < KP)                      // Poisson(4): never >32
        Qraw[(c << 5) + slot] = make_float4(p.x, p.y, __int_as_float(tid), h);
}

// ROW-LOCAL ordered emit: thread (c,s) handles arrival slots s, s+8, ...
// All reads are the cell's own Qraw row (L1-hot, coalesced across the 8
// sibling threads); NO random gathers (pos/h travel inside the record).
// rank = #(smaller ids in row) puts each record at its id-sorted position
// (stable argsort semantics). S = exact f32 threshold:
//   s2 <= S  <=>  RN(sqrt(s2)) <= h
// mid = (h + nextafterf(h))/2; mid^2 exact in double (50 bits), never a
// 24-bit f32 -> no ties; S = largest f32 <= mid^2. (verified since r2)
__global__ __launch_bounds__(256) void rank_kernel(
        const int* __restrict__ counts, const float4* __restrict__ Qraw,
        float4* __restrict__ Qpad, int* __restrict__ linR,
        int4* __restrict__ cinfo) {
    int tid = blockIdx.x * 256 + threadIdx.x;   // NUM_CELLS*8 threads
    int c   = tid >> 3;
    int s0  = tid & 7;
    int cnt = min(counts[c], KP);
    const float4* row = Qraw + (c << 5);
    for (int sl = s0; sl < cnt; sl += 8) {
        float4 rec = row[sl];
        int id = __float_as_int(rec.z);
        int rank = 0;
        for (int k = 0; k < cnt; k++)
            rank += (__float_as_int(row[k].z) < id);
        float h = rec.w;
        float  hn  = __int_as_float(__float_as_int(h) + 1); // nextafter(h,inf)
        double mid = 0.5 * ((double)h + (double)hn);
        double t2  = mid * mid;                              // exact
        float  S   = (float)t2;                              // RN
        S = ((double)S > t2) ? __int_as_float(__float_as_int(S) - 1) : S;
        Qpad[(c << 5) + rank] = make_float4(rec.x, rec.y, rec.z, S);
        linR[id] = (c << 5) | rank;     // rank < 32: fits 5 bits
    }
    if (s0 == 0) {                      // one thread per cell: prefix sums
        const int offs[9] = {-257, -1, 255, -256, 0, 256, -255, 1, 257};
        int cum = 0;
        int v[9];
#pragma unroll
        for (int o = 0; o < 9; o++) {
            int cl = min(max(c + offs[o], 0), NUM_CELLS);   // clip, dups incl.
            cum += min(counts[cl], KP);
            v[o] = cum;
        }
        cinfo[(c << 2) + 0] = make_int4(v[0], v[1], v[2], v[3]);
        cinfo[(c << 2) + 1] = make_int4(v[4], v[5], v[6], v[7]);
        cinfo[(c << 2) + 2] = make_int4(v[8], 0, 0, 0);
    }
}

// One wave per PARTICLE in ID ORDER (r10-verified body, 102.7us): linR ->
// own record (px,py,S) -> one 64B cinfo line -> register window gather ->
// masked-ballot stable compaction -> LDS bounce -> sequential 256B row
// stores. Junk lanes (>=T) clamp to the own-record line (always written).
__global__ __launch_bounds__(256) void query_kernel(
        const int* __restrict__ linR, const int4* __restrict__ cinfo,
        const float4* __restrict__ Qpad,
        float* __restrict__ outN, float* __restrict__ outC,
        float* __restrict__ outR) {
#pragma clang fp contract(off)
    __shared__ int   s_id[4][MAXNB];
    __shared__ float s_s2[4][MAXNB];

    int t    = threadIdx.x;
    int lane = t & 63;
    int wsl  = t >> 6;
    int bid  = blockIdx.x;
    int swz  = (bid & 7) * (int)(gridDim.x >> 3) + (bid >> 3);  // bijective XCD
    int w    = __builtin_amdgcn_readfirstlane(swz * 4 + wsl);   // particle id

    int lr = __builtin_amdgcn_readfirstlane(linR[w]);
    int c  = lr >> 5;

    int4 ca = cinfo[(c << 2) + 0];      // one 64B line, uniform
    int4 cb = cinfo[(c << 2) + 1];
    int4 cz = cinfo[(c << 2) + 2];
    float4 me = Qpad[lr];               // own record: {x, y, id-bits, S}
    float px = me.x, py = me.y, S = me.w;

    const int offs[9] = {-257, -1, 255, -256, 0, 256, -255, 1, 257};
    int cum[10] = {0, ca.x, ca.y, ca.z, ca.w, cb.x, cb.y, cb.z, cb.w, };
    cum[9] = cz.x;
    int T = cum[9];
    int delta[9];
#pragma unroll
    for (int o = 0; o < 9; o++) {
        int cl = min(max(c + offs[o], 0), NUM_CELLS);   // clip, dups at edges
        delta[o] = (cl << 5) - cum[o];                  // idx = ll + delta[o]
    }

    if (T <= 64) {
        // ---- fast path: one candidate per lane ----
        int dsel = delta[0];
#pragma unroll
        for (int m = 1; m < 9; m++)
            dsel = (lane >= cum[m]) ? delta[m] : dsel;
        int idx = (lane < T) ? (lane + dsel) : lr;      // clamp junk lanes to
        float4 q = Qpad[idx];                           //  the hot own-line
        unsigned long long maskT = (T >= 64) ? ~0ull : ((1ull << T) - 1ull);
        float dx = q.x - px;
        float dy = q.y - py;
        float s2 = dx * dx + dy * dy;          // contract(off): match XLA
        bool keep = (s2 <= S) && (lane < T);   // junk/clamp lanes masked
        unsigned long long bal = __ballot(s2 <= S) & maskT;
        int rank = __builtin_amdgcn_mbcnt_hi(
            (unsigned)(bal >> 32),
            __builtin_amdgcn_mbcnt_lo((unsigned)bal, 0));
        if (keep) {                            // T<=64 -> rank < 64 always
            s_id[wsl][rank] = __float_as_int(q.z);
            s_s2[wsl][rank] = s2;
        }
        int total = (int)__popcll(bal);
        // wave-private LDS, same-wave DS ops ordered: no barrier. Stale
        // entries beyond 'total' discarded by the inb select.
        int   jj = s_id[wsl][lane];
        float ss = s_s2[wsl][lane];
        bool inb = lane < total;
        float rh = __builtin_amdgcn_rsqf(S);   // ~1/h, 1ulp; tol-covered
        float vN = inb ? (float)jj : -1.0f;
        float vR = inb ? __builtin_amdgcn_sqrtf(ss) * rh : 0.0f;
        size_t base = (size_t)w * MAXNB;       // SEQUENTIAL across waves
        outN[base + lane] = vN;
        outR[base + lane] = vR;
        if (lane == 0) outC[w] = (float)total;
    } else {
        // ---- rare path (P(T>64) ~ 1e-5 per cell): batched, re-loads ----
        int total = 0;
        for (int b0 = 0; b0 < T; b0 += 64) {
            int ll = b0 + lane;
            int dsel = delta[0];
#pragma unroll
            for (int m = 1; m < 9; m++)
                dsel = (ll >= cum[m]) ? delta[m] : dsel;
            float4 q = Qpad[ll + dsel];        // in-bounds: slot<32, cl<=NC
            float dx = q.x - px;
            float dy = q.y - py;
            float s2 = dx * dx + dy * dy;
            int rem = T - b0;
            unsigned long long maskT =
                (rem >= 64) ? ~0ull : ((1ull << rem) - 1ull);
            unsigned long long bal = __ballot(s2 <= S) & maskT;
            int rank = __builtin_amdgcn_mbcnt_hi(
                (unsigned)(bal >> 32),
                __builtin_amdgcn_mbcnt_lo((unsigned)bal, 0));
            int ww = total + rank;
            if ((s2 <= S) && (ll < T) && (ww < MAXNB)) {
                s_id[wsl][ww] = __float_as_int(q.z);
                s_s2[wsl][ww] = s2;
            }
            total += (int)__popcll(bal);
        }
        int stored = min(total, MAXNB);
        int   jj = s_id[wsl][lane];
        float ss = s_s2[wsl][lane];
        bool inb = lane < stored;
        float rh = __builtin_amdgcn_rsqf(S);
        float vN = inb ? (float)jj : -1.0f;
        float vR = inb ? __builtin_amdgcn_sqrtf(ss) * rh : 0.0f;
        size_t base = (size_t)w * MAXNB;
        outN[base + lane] = vN;
        outR[base + lane] = vR;
        if (lane == 0) outC[w] = (float)total;
    }
}

extern "C" void kernel_launch(void* const* d_in, const int* in_sizes, int n_in,
                              void* d_out, int out_size, void* d_ws, size_t ws_size,
                              hipStream_t stream) {
    const float2* pos2 = (const float2*)d_in[0];
    const float*  sup  = (const float*)d_in[1];

    char* p = (char*)d_ws;
    auto alloc = [&](size_t bytes) {
        char* q = p;
        p += (bytes + 255) & ~(size_t)255;
        return q;
    };
    unsigned* params = (unsigned*)alloc(256);
    int*    counts = (int*)alloc((size_t)(NUM_CELLS + 1) * 4);
    float*  bMinX  = (float*)alloc(1024 * 4);
    float*  bMinY  = (float*)alloc(1024 * 4);
    float*  bMaxH  = (float*)alloc(1024 * 4);
    float4* Qraw   = (float4*)alloc((size_t)(NUM_CELLS + 1) * KP * 16);
    float4* Qpad   = (float4*)alloc(((size_t)(NUM_CELLS + 1) * KP + 64) * 16);
    int*    linR   = (int*)alloc((size_t)N_PART * 4);
    int4*   cinfo  = (int4*)alloc((size_t)NUM_CELLS * 4 * 16);

    float* out  = (float*)d_out;
    float* outN = out;                              // N*64 neighbor ids (as f32)
    float* outC = out + (size_t)N_PART * MAXNB;     // N counts
    float* outR = outC + N_PART;                    // N*64 radial

    prep_kernel<<<N_PART / 256, 256, 0, stream>>>(pos2, sup, counts,
                                                  bMinX, bMinY, bMaxH);
    bin_kernel<<<N_PART / 256, 256, 0, stream>>>(pos2, sup, bMinX, bMinY,
                                                 bMaxH, params, counts, Qraw);
    // thread per (cell, slot-class): NUM_CELLS*8 threads
    rank_kernel<<<NUM_CELLS * 8 / 256, 256, 0, stream>>>(counts, Qraw,
                                                         Qpad, linR, cinfo);
    // one wave per particle, ID ORDER: N_PART waves = N_PART/4 blocks
    query_kernel<<<N_PART / 4, 256, 0, stream>>>(linR, cinfo, Qpad,
                                                 outN, outC, outR);
}